// Round 4
// baseline (24.450 us; speedup 1.0000x reference)
//
#include <hip/hip_runtime.h>

// N=65536 rows, D=256 fp32. out[row] = -dot(q[row], d[row]).
//
// 4 rows per wave, full 64 lanes per row: one row = 64 lanes x float4 = 1 KB,
// so every load instruction is a single fully-contiguous 1 KB segment (ideal
// coalescing). 8 independent loads in flight per lane (128 B). Four 6-step
// shuffle reductions interleaved; lane 0 stores the 4 consecutive outputs as
// one float4. One-shot grid: 16 rows/block x 4096 blocks.

__global__ __launch_bounds__(256) void neg_rowdot_kernel(
    const float* __restrict__ q,
    const float* __restrict__ d,
    float* __restrict__ out)
{
    const int lane = threadIdx.x & 63;
    const int wave = threadIdx.x >> 6;     // 0..3

    const int base_row = blockIdx.x * 16 + wave * 4;   // 4 consecutive rows

    const float4* q4 = reinterpret_cast<const float4*>(q) + (size_t)base_row * 64;
    const float4* d4 = reinterpret_cast<const float4*>(d) + (size_t)base_row * 64;

    // 8 independent full-wave-contiguous loads (each instr covers 1 KB).
    float4 a0 = q4[lane];
    float4 a1 = q4[lane + 64];
    float4 a2 = q4[lane + 128];
    float4 a3 = q4[lane + 192];
    float4 b0 = d4[lane];
    float4 b1 = d4[lane + 64];
    float4 b2 = d4[lane + 128];
    float4 b3 = d4[lane + 192];

    float s0 = a0.x * b0.x + a0.y * b0.y + a0.z * b0.z + a0.w * b0.w;
    float s1 = a1.x * b1.x + a1.y * b1.y + a1.z * b1.z + a1.w * b1.w;
    float s2 = a2.x * b2.x + a2.y * b2.y + a2.z * b2.z + a2.w * b2.w;
    float s3 = a3.x * b3.x + a3.y * b3.y + a3.z * b3.z + a3.w * b3.w;

    // Four interleaved 6-step wave-64 reductions.
    s0 += __shfl_xor(s0, 32, 64);
    s1 += __shfl_xor(s1, 32, 64);
    s2 += __shfl_xor(s2, 32, 64);
    s3 += __shfl_xor(s3, 32, 64);
    s0 += __shfl_xor(s0, 16, 64);
    s1 += __shfl_xor(s1, 16, 64);
    s2 += __shfl_xor(s2, 16, 64);
    s3 += __shfl_xor(s3, 16, 64);
    s0 += __shfl_xor(s0, 8, 64);
    s1 += __shfl_xor(s1, 8, 64);
    s2 += __shfl_xor(s2, 8, 64);
    s3 += __shfl_xor(s3, 8, 64);
    s0 += __shfl_xor(s0, 4, 64);
    s1 += __shfl_xor(s1, 4, 64);
    s2 += __shfl_xor(s2, 4, 64);
    s3 += __shfl_xor(s3, 4, 64);
    s0 += __shfl_xor(s0, 2, 64);
    s1 += __shfl_xor(s1, 2, 64);
    s2 += __shfl_xor(s2, 2, 64);
    s3 += __shfl_xor(s3, 2, 64);
    s0 += __shfl_xor(s0, 1, 64);
    s1 += __shfl_xor(s1, 1, 64);
    s2 += __shfl_xor(s2, 1, 64);
    s3 += __shfl_xor(s3, 1, 64);

    if (lane == 0) {
        float4 r = make_float4(-s0, -s1, -s2, -s3);
        *reinterpret_cast<float4*>(out + base_row) = r;
    }
}

extern "C" void kernel_launch(void* const* d_in, const int* in_sizes, int n_in,
                              void* d_out, int out_size, void* d_ws, size_t ws_size,
                              hipStream_t stream) {
    const float* q = (const float*)d_in[0];
    const float* d = (const float*)d_in[1];
    float* out = (float*)d_out;

    const int n_rows = out_size;                  // 65536
    const int rows_per_block = 16;                // 4 waves x 4 rows
    int grid = n_rows / rows_per_block;           // 4096

    neg_rowdot_kernel<<<grid, 256, 0, stream>>>(q, d, out);
}